// Round 3
// baseline (91.437 us; speedup 1.0000x reference)
//
#include <hip/hip_runtime.h>

#define B_DIM 256
#define E_DIM 8192
#define C_DIM 19
#define XBLK  32                 // E_DIM / B_DIM
#define NBLK  (XBLK * C_DIM)     // 608 blocks total

// ws layout (floats). Published slots carry a +1.0f sentinel so "written" is
// detectable against the 0xAA poison (0xAAAAAAAA as float = -3.03e-13 < 1.0f).
//  [0   .. 607 ]  capP[c*32+x] + 1.0   partial count of (e_true>=0.5)
//  [608 .. 626 ]  n_pos[c]             (published via m-slot release chain)
//  [627 .. 645 ]  sum_yp[c]
//  [646 .. 1253]  mP[c*32+x] + 1.0     partial weighted pair sum
#define WS_CAP  0
#define WS_NPOS 608
#define WS_SYP  627
#define WS_M    646

#define SPIN_GUARD (1 << 28)   // bounded spin: wrong answer beats a hang

__device__ __forceinline__ float agent_load_acq(const float* p) {
    return __hip_atomic_load(p, __ATOMIC_ACQUIRE, __HIP_MEMORY_SCOPE_AGENT);
}
__device__ __forceinline__ void agent_store_rel(float* p, float v) {
    __hip_atomic_store(p, v, __ATOMIC_RELEASE, __HIP_MEMORY_SCOPE_AGENT);
}

// Block-wide sum (256 threads = 4 waves). Result valid on tid==0 only.
__device__ __forceinline__ float block_sum(float v, int tid, float* red4) {
    #pragma unroll
    for (int off = 32; off > 0; off >>= 1) v += __shfl_down(v, off, 64);
    if ((tid & 63) == 0) red4[tid >> 6] = v;
    __syncthreads();
    float r = 0.0f;
    if (tid == 0) r = red4[0] + red4[1] + red4[2] + red4[3];
    __syncthreads();
    return r;
}

__global__ void __launch_bounds__(B_DIM)
rocstar_fused(const float* __restrict__ y_pred,
              const float* __restrict__ y_true,
              const float* __restrict__ epoch_pred,
              const float* __restrict__ epoch_true,
              const float* __restrict__ gamma,
              const float* __restrict__ rand_pos,
              const float* __restrict__ rand_neg,
              float* __restrict__ ws,
              float* __restrict__ out) {
    const int c   = blockIdx.y;
    const int x   = blockIdx.x;
    const int tid = threadIdx.x;
    const int j   = x * B_DIM + tid;

    __shared__ float4 s_yp4[B_DIM / 2];   // {yp_i, pm_i, yp_{i+1}, pm_{i+1}}
    __shared__ float  red4[4];
    __shared__ float  s_cap[XBLK];

    // ---- loads (all stride-C_DIM columns; small, L2-resident) ----
    const float yp = y_pred[tid * C_DIM + c];
    const float pm = (y_true[tid * C_DIM + c] >= 0.5f) ? 1.0f : 0.0f;
    ((float2*)s_yp4)[tid] = make_float2(yp, pm);

    const float ep = epoch_pred[j * C_DIM + c];
    const bool  et = epoch_true[j * C_DIM + c] >= 0.5f;
    const float rp = rand_pos[j * C_DIM + c];
    const float rn = rand_neg[j * C_DIM + c];
    const float g  = gamma[c];

    // ---- publish this slice's cap partial (count of epoch positives) ----
    const float cs = block_sum(et ? 1.0f : 0.0f, tid, red4);  // syncs -> s_yp4 ready
    if (tid == 0) agent_store_rel(&ws[WS_CAP + c * XBLK + x], cs + 1.0f);

    // x==0 blocks also own the B-reductions; published by the m-slot release.
    if (x == 0) {
        const float np = block_sum(pm, tid, red4);
        if (tid == 0) ws[WS_NPOS + c] = np;
        const float sy = block_sum(yp, tid, red4);
        if (tid == 0) ws[WS_SYP + c] = sy;
    }

    // ---- pair loop: p-independent combined form ----
    // et=0 (epoch neg, m2): d = (ep - yp) + g, mask = pm      -> s = +1
    // et=1 (epoch pos, m3): d = (yp - ep) + g, mask = 1 - pm  -> s = -1
    const float s    = et ? -1.0f : 1.0f;
    const float a    = fmaf(s, ep, g);        // s*ep + g
    const float ns   = -s;
    const float et01 = et ? 1.0f : 0.0f;

    float acc0 = 0.0f, acc1 = 0.0f;
    #pragma unroll 8
    for (int k = 0; k < B_DIM / 2; ++k) {
        const float4 v = s_yp4[k];            // broadcast ds_read_b128
        float d0 = fmaxf(fmaf(ns, v.x, a), 0.0f);
        float m0 = fmaf(s, v.y, et01);        // pm or 1-pm
        acc0 = fmaf(d0 * d0, m0, acc0);
        float d1 = fmaxf(fmaf(ns, v.z, a), 0.0f);
        float m1 = fmaf(s, v.w, et01);
        acc1 = fmaf(d1 * d1, m1, acc1);
    }

    // ---- now fetch cap (normally already published by all 32 slice-blocks) ----
    if (tid < XBLK) {
        float v; int guard = 0;
        do { v = agent_load_acq(&ws[WS_CAP + c * XBLK + tid]); }
        while (v < 1.0f && ++guard < SPIN_GUARD);
        s_cap[tid] = v - 1.0f;
    }
    __syncthreads();
    float cap = 0.0f;
    #pragma unroll
    for (int t = 0; t < XBLK; ++t) cap += s_cap[t];   // fixed order, all threads agree

    const float p = 1000.0f / fmaxf(cap, 1.0f);       // MAX_POS / cap_pos (f32, as ref)
    // faithful to the reference "bug": both masks use p from cap_pos
    const float r = et ? rp : rn;
    const float w = (r < p) ? 1.0f : 0.0f;

    const float bs = block_sum(w * (acc0 + acc1), tid, red4);
    if (tid == 0) agent_store_rel(&ws[WS_M + c * XBLK + x], bs + 1.0f);

    // ---- block (0,0): wait for all 608 m-partials, then finalize ----
    if (x == 0 && c == 0) {
        for (int sl = tid; sl < NBLK; sl += B_DIM) {
            float v; int guard = 0;
            do { v = agent_load_acq(&ws[WS_M + sl]); }
            while (v < 1.0f && ++guard < SPIN_GUARD);
        }
        __syncthreads();

        if (tid < 64) {
            float rv = 0.0f;
            if (tid < C_DIM) {
                float m = 0.0f;
                #pragma unroll
                for (int t = 0; t < XBLK; ++t)
                    m += agent_load_acq(&ws[WS_M + tid * XBLK + t]) - 1.0f;
                float v = m / 1000.0f;                 // m2/MAX_POS + m3/MAX_NEG
                if (isnan(v)) v = 0.0f;
                const float np = agent_load_acq(&ws[WS_NPOS + tid]);
                const float sy = agent_load_acq(&ws[WS_SYP + tid]);
                rv = (np == 0.0f || np == (float)B_DIM) ? sy * 1e-8f : v;
            }
            #pragma unroll
            for (int off = 16; off > 0; off >>= 1) rv += __shfl_down(rv, off, 64);
            if (tid == 0) out[0] = rv / (float)C_DIM;  // mean over classes
        }
    }
}

extern "C" void kernel_launch(void* const* d_in, const int* in_sizes, int n_in,
                              void* d_out, int out_size, void* d_ws, size_t ws_size,
                              hipStream_t stream) {
    const float* y_pred     = (const float*)d_in[0];
    const float* y_true     = (const float*)d_in[1];
    const float* epoch_pred = (const float*)d_in[2];
    const float* epoch_true = (const float*)d_in[3];
    const float* gamma      = (const float*)d_in[4];
    const float* rand_pos   = (const float*)d_in[5];
    const float* rand_neg   = (const float*)d_in[6];
    float*       out        = (float*)d_out;
    float*       ws         = (float*)d_ws;

    const dim3 grid(XBLK, C_DIM);   // 32 x 19 = 608 blocks, all co-resident
    rocstar_fused<<<grid, B_DIM, 0, stream>>>(y_pred, y_true, epoch_pred, epoch_true,
                                              gamma, rand_pos, rand_neg, ws, out);
}